// Round 1
// baseline (10565.450 us; speedup 1.0000x reference)
//
#include <hip/hip_runtime.h>

#define NB 512
#define NL 512
#define NK 103
#define NH 512

typedef _Float16 half8 __attribute__((ext_vector_type(8)));
typedef float floatx4 __attribute__((ext_vector_type(4)));

// LDS layout (bytes). 160 KiB/CU on gfx950.
// B1: 128 cols x 520 f16 (gates 0..63 = i,f,g,o x16 for h-slice; 64..127 = W1 rows), pad +8 kills bank conflicts
// B2: 64 cols x 136 f16 (W_ih x-part, rows >=103 zeroed)
// YST: 64 x 72 f16 scratch for MLP; W2h: 16x64 f16; FR: small fp32 tables
#define B1_STR 520
#define B2_STR 136
#define YST_STR 72
#define OFF_B1 0
#define OFF_B2 133120
#define OFF_YST 150528
#define OFF_W2 159744
#define OFF_F32 161792
#define SMEM_BYTES 163528

__device__ __forceinline__ float fast_sigmoid(float v) {
  v = fminf(fmaxf(v, -30.f), 30.f);
  return __builtin_amdgcn_rcpf(1.f + __expf(-v));
}
__device__ __forceinline__ float fast_tanh(float v) {
  v = fminf(fmaxf(v, -15.f), 15.f);
  float e = __expf(-2.f * v);
  return (1.f - e) * __builtin_amdgcn_rcpf(1.f + e);
}

__global__ void __launch_bounds__(256, 1)
lstm_persist(const float* __restrict__ x, const float* __restrict__ pos,
             const float* __restrict__ h0, const float* __restrict__ c0,
             const float* __restrict__ Wih, const float* __restrict__ Whh,
             const float* __restrict__ bih, const float* __restrict__ bhh,
             const float* __restrict__ W1, const float* __restrict__ b1,
             const float* __restrict__ W2, const float* __restrict__ b2,
             const float* __restrict__ W3, const float* __restrict__ b3,
             float* __restrict__ out, void* __restrict__ ws)
{
  extern __shared__ char smem[];
  _Float16* B1s = (_Float16*)(smem + OFF_B1);
  _Float16* B2s = (_Float16*)(smem + OFF_B2);
  _Float16* YST = (_Float16*)(smem + OFF_YST);
  _Float16* W2h = (_Float16*)(smem + OFF_W2);
  float* FR  = (float*)(smem + OFF_F32);
  float* b1s = FR;          // 64
  float* b2s = FR + 64;     // 16
  float* w3s = FR + 80;     // 32
  float* b3s = FR + 112;    // 2
  float* wy0 = FR + 114;    // 64  W_ih[:,103] slice
  float* wy1 = FR + 178;    // 64  W_ih[:,104] slice
  float* bgs = FR + 242;    // 64  b_ih+b_hh slice
  float* ypres = FR + 306;  // 128 fed-back pos per local row

  const int tid = threadIdx.x;
  const int g  = blockIdx.x >> 5;   // batch group: rows 64g..64g+63
  const int cs = blockIdx.x & 31;   // h-column slice: 16cs..16cs+15
  const int l = tid & 63, quad = l >> 4, c16 = l & 15;
  const int w = tid >> 6;

  unsigned* cnt = (unsigned*)ws + (size_t)g * 64;  // 256B-spaced per-group barrier counters
  _Float16* hbuf = (_Float16*)((char*)ws + 4096);  // 2 x [512][512] f16, double-buffered h
  const int HB = NB * NH;

  // ---- stage weights into LDS (fp16), once ----
  for (int idx = tid; idx < 128 * 512; idx += 256) {
    int cc = idx >> 9, k = idx & 511;
    float v;
    if (cc < 64) {
      int gr = (cc >> 4) * NH + cs * 16 + (cc & 15);   // gate row: type*512 + slice
      v = Whh[(size_t)gr * NH + k];
    } else {
      v = W1[(size_t)(cc - 64) * NH + k];
    }
    B1s[cc * B1_STR + k] = (_Float16)v;
  }
  for (int idx = tid; idx < 64 * 128; idx += 256) {
    int cc = idx >> 7, k = idx & 127;
    int gr = (cc >> 4) * NH + cs * 16 + (cc & 15);
    float v = (k < NK) ? Wih[(size_t)gr * 105 + k] : 0.f;  // zero-pad 103->128
    B2s[cc * B2_STR + k] = (_Float16)v;
  }
  for (int idx = tid; idx < 16 * 64; idx += 256)
    W2h[idx] = (_Float16)W2[idx];
  if (tid < 64) {
    int gr = (tid >> 4) * NH + cs * 16 + (tid & 15);
    wy0[tid] = Wih[(size_t)gr * 105 + 103];
    wy1[tid] = Wih[(size_t)gr * 105 + 104];
    bgs[tid] = bih[gr] + bhh[gr];
    b1s[tid] = b1[tid];
  }
  if (tid < 16) b2s[tid] = b2[tid];
  if (tid < 32) w3s[tid] = W3[tid];
  if (tid < 2)  b3s[tid] = b3[tid];

  // init h buffer 0 with initial hidden state (this wg's slice)
  for (int idx = tid; idx < 1024; idx += 256) {
    int r = idx >> 4, cl = idx & 15;
    int row = g * 64 + r, col = cs * 16 + cl;
    hbuf[(size_t)row * NH + col] = (_Float16)h0[(size_t)row * NH + col];
  }

  const int hcol = cs * 16 + c16;        // owned h column for this lane
  const int rl0 = w * 16 + quad * 4;     // local row base (MFMA C-layout)
  const int arow = g * 64 + w * 16 + c16; // A-fragment row (MFMA A-layout m=lane&15)

  float cacc[4];                         // cell state stays fp32 in registers
  #pragma unroll
  for (int r = 0; r < 4; ++r)
    cacc[r] = c0[(size_t)(g * 64 + rl0 + r) * NH + hcol];

  int ep = 1;
  auto gbar = [&](void) {                // 32-wg group barrier, agent scope
    __syncthreads();
    if (tid == 0) {
      __hip_atomic_fetch_add(cnt, 1u, __ATOMIC_RELEASE, __HIP_MEMORY_SCOPE_AGENT);
      const unsigned tgt = (unsigned)(32 * ep);
      while (__hip_atomic_load(cnt, __ATOMIC_ACQUIRE, __HIP_MEMORY_SCOPE_AGENT) < tgt)
        __builtin_amdgcn_s_sleep(2);
    }
    __syncthreads();
    ep++;
  };

  gbar();  // h init visible group-wide

  // iteration t: computes y_{t-1}=MLP(h_{t-1}) (t>0), gates(t) from [h_{t-1}, x_t, y_{t-1}],
  // cell update -> h_t. Iteration NL only produces y_{NL-1}.
  for (int t = 0; t <= NL; ++t) {
    const _Float16* hr = hbuf + (size_t)(t & 1) * HB;
    _Float16* hw = hbuf + (size_t)((t + 1) & 1) * HB;

    floatx4 acc[8] = {};

    // phase 1: K = 0..511 (h_{t-1}) -> 4 gate tiles + 4 MLP-layer1 tiles
    {
      const _Float16* hrow = hr + (size_t)arow * NH + quad * 8;
      half8 afr[16];
      #pragma unroll
      for (int kk = 0; kk < 16; ++kk)
        afr[kk] = *(const half8*)(hrow + kk * 32);
      #pragma unroll
      for (int kk = 0; kk < 16; ++kk) {
        const int kb = kk * 32 + quad * 8;
        #pragma unroll
        for (int tt = 0; tt < 8; ++tt) {
          half8 bf = *(const half8*)(B1s + (tt * 16 + c16) * B1_STR + kb);
          acc[tt] = __builtin_amdgcn_mfma_f32_16x16x32_f16(afr[kk], bf, acc[tt], 0, 0, 0);
        }
      }
    }

    // phase 2: K from x_t (103, zero-padded to 128), gates only
    if (t < NL) {
      const float* xrow = x + (size_t)arow * (NL * NK) + (size_t)t * NK + quad * 8;
      #pragma unroll
      for (int kb = 0; kb < 4; ++kb) {
        half8 af;
        #pragma unroll
        for (int j = 0; j < 8; ++j) {
          int k = kb * 32 + quad * 8 + j;
          float v = (k < NK) ? xrow[kb * 32 + j] : 0.f;
          af[j] = (_Float16)v;
        }
        #pragma unroll
        for (int tt = 0; tt < 4; ++tt) {
          half8 bf = *(const half8*)(B2s + (tt * 16 + c16) * B2_STR + kb * 32 + quad * 8);
          acc[tt] = __builtin_amdgcn_mfma_f32_16x16x32_f16(af, bf, acc[tt], 0, 0, 0);
        }
      }
    }

    // ---- fed-back pos: t==0 uses pos[:,0,:], else MLP layers 2/3 on layer-1 acc ----
    if (t == 0) {
      if (tid < 128)
        ypres[tid] = pos[(size_t)(g * 64 + (tid >> 1)) * (NL * 2) + (tid & 1)];
      __syncthreads();
    } else {
      #pragma unroll
      for (int tm = 0; tm < 4; ++tm) {
        #pragma unroll
        for (int r = 0; r < 4; ++r) {
          float v = acc[4 + tm][r] + b1s[tm * 16 + c16];
          YST[(rl0 + r) * YST_STR + tm * 16 + c16] = (_Float16)fmaxf(v, 0.f);
        }
      }
      __syncthreads();
      const int rl2 = tid >> 2;
      const half8* yrow = (const half8*)(YST + rl2 * YST_STR);
      float y2v[4];
      #pragma unroll
      for (int q = 0; q < 4; ++q) {
        int m2 = (tid & 3) * 4 + q;
        const half8* wrow = (const half8*)(W2h + m2 * 64);
        float s = b2s[m2];
        #pragma unroll
        for (int kv = 0; kv < 8; ++kv) {
          half8 av = yrow[kv], bv = wrow[kv];
          #pragma unroll
          for (int j = 0; j < 8; ++j)
            s += (float)av[j] * (float)bv[j];
        }
        y2v[q] = fmaxf(s, 0.f);
      }
      __syncthreads();
      #pragma unroll
      for (int q = 0; q < 4; ++q)
        YST[rl2 * YST_STR + (tid & 3) * 4 + q] = (_Float16)y2v[q];
      __syncthreads();
      if (tid < 128) {
        int rl = tid >> 1, o = tid & 1;
        float s = b3s[o];
        #pragma unroll
        for (int k = 0; k < 16; ++k)
          s += (float)YST[rl * YST_STR + k] * w3s[o * 16 + k];
        ypres[tid] = fmaxf(s, 0.f);
      }
      __syncthreads();
    }

    // predicted_pos[:, t-1, :] = y_{t-1}
    if (t > 0 && cs == 0 && tid < 128)
      out[(size_t)(g * 64 + (tid >> 1)) * (NL * 2) + (size_t)(t - 1) * 2 + (tid & 1)] = ypres[tid];

    if (t < NL) {
      // rank-2 y feedback + bias + LSTM cell
      #pragma unroll
      for (int r = 0; r < 4; ++r) {
        const int rl = rl0 + r;
        const float yp0 = ypres[rl * 2], yp1 = ypres[rl * 2 + 1];
        float gi = acc[0][r] + bgs[c16]      + yp0 * wy0[c16]      + yp1 * wy1[c16];
        float gf = acc[1][r] + bgs[16 + c16] + yp0 * wy0[16 + c16] + yp1 * wy1[16 + c16];
        float gg = acc[2][r] + bgs[32 + c16] + yp0 * wy0[32 + c16] + yp1 * wy1[32 + c16];
        float go = acc[3][r] + bgs[48 + c16] + yp0 * wy0[48 + c16] + yp1 * wy1[48 + c16];
        float iv = fast_sigmoid(gi);
        float fv = fast_sigmoid(gf);
        float gv = fast_tanh(gg);
        float ov = fast_sigmoid(go);
        float cn = fv * cacc[r] + iv * gv;
        cacc[r] = cn;
        float hn = ov * fast_tanh(cn);
        hw[(size_t)(g * 64 + rl) * NH + hcol] = (_Float16)hn;
        if (t == NL - 1) {
          out[(size_t)(NB * NL * 2) + (size_t)(g * 64 + rl) * NH + hcol] = hn;
          out[(size_t)(NB * NL * 2) + (size_t)(NB * NH) + (size_t)(g * 64 + rl) * NH + hcol] = cn;
        }
      }
      gbar();  // h_t visible to the group before next step reads it
    }
  }
}

extern "C" void kernel_launch(void* const* d_in, const int* in_sizes, int n_in,
                              void* d_out, int out_size, void* d_ws, size_t ws_size,
                              hipStream_t stream) {
  (void)in_sizes; (void)n_in; (void)out_size; (void)ws_size;
  const float* x   = (const float*)d_in[0];
  const float* pos = (const float*)d_in[1];
  const float* h0  = (const float*)d_in[2];
  const float* c0  = (const float*)d_in[3];
  const float* Wih = (const float*)d_in[4];
  const float* Whh = (const float*)d_in[5];
  const float* bih = (const float*)d_in[6];
  const float* bhh = (const float*)d_in[7];
  const float* W1  = (const float*)d_in[8];
  const float* b1  = (const float*)d_in[9];
  const float* W2  = (const float*)d_in[10];
  const float* b2  = (const float*)d_in[11];
  const float* W3  = (const float*)d_in[12];
  const float* b3  = (const float*)d_in[13];
  float* out = (float*)d_out;

  // zero the group-barrier counters (ws is re-poisoned 0xAA before every launch)
  hipMemsetAsync(d_ws, 0, 4096, stream);

  hipFuncSetAttribute(reinterpret_cast<const void*>(lstm_persist),
                      hipFuncAttributeMaxDynamicSharedMemorySize, SMEM_BYTES);

  void* args[] = { (void*)&x, (void*)&pos, (void*)&h0, (void*)&c0,
                   (void*)&Wih, (void*)&Whh, (void*)&bih, (void*)&bhh,
                   (void*)&W1, (void*)&b1, (void*)&W2, (void*)&b2,
                   (void*)&W3, (void*)&b3, (void*)&out, (void*)&d_ws };

  hipLaunchCooperativeKernel(reinterpret_cast<void*>(lstm_persist),
                             dim3(256, 1, 1), dim3(256, 1, 1),
                             args, (unsigned)SMEM_BYTES, stream);
}